// Round 1
// baseline (21.369 us; speedup 1.0000x reference)
//
#include <hip/hip_runtime.h>

#define GSZ  97
#define NPTS (GSZ * GSZ)
#define DVOL 150
#define HVOL 512
#define WVOL 512

struct Basis {
    float pvx, pvy, pvz;
    float pwx, pwy, pwz;
    float nx,  ny,  nz;
    float ox,  oy,  oz;
};

// Compute the polar-rotated sampled field (f_pol, 3 values) at grid point (h, w).
// Optionally also return the vwn-projected field (f_p, 3 values) via fproj.
__device__ inline void fpol_at(const float* __restrict__ f, int h, int w,
                               const Basis& B, float* __restrict__ fpol,
                               float* __restrict__ fproj)
{
    const float gv = (float)(w - 48);   // v value = gxy[w]
    const float gw = (float)(h - 48);   // w value = gxy[h]

    // world-space sample position
    const float px = gv * B.pvx + gw * B.pwx + B.ox;
    const float py = gv * B.pvy + gw * B.pwy + B.oy;
    const float pz = gv * B.pvz + gw * B.pwz + B.oz;

    // normalized -> fractional voxel index (same arithmetic as reference)
    const float EPSF = 1e-8f;
    const float gnx = px * (2.0f / ((float)WVOL - 1.0f + EPSF)) - 1.0f;
    const float gny = py * (2.0f / ((float)HVOL - 1.0f + EPSF)) - 1.0f;
    const float gnz = pz * (2.0f / ((float)DVOL - 1.0f + EPSF)) - 1.0f;
    const float ix = ((gnx + 1.0f) * (float)WVOL - 1.0f) * 0.5f;
    const float iy = ((gny + 1.0f) * (float)HVOL - 1.0f) * 0.5f;
    const float iz = ((gnz + 1.0f) * (float)DVOL - 1.0f) * 0.5f;

    const float x0f = floorf(ix), y0f = floorf(iy), z0f = floorf(iz);
    const float wx = ix - x0f, wy = iy - y0f, wz = iz - z0f;
    const int x0 = (int)x0f, y0 = (int)y0f, z0 = (int)z0f;

    const size_t cstride = (size_t)DVOL * HVOL * WVOL;

    float acc0 = 0.0f, acc1 = 0.0f, acc2 = 0.0f;
#pragma unroll
    for (int dz = 0; dz < 2; ++dz) {
        const float wgz = dz ? wz : 1.0f - wz;
        const int zc = z0 + dz;
        const bool vz = (zc >= 0) && (zc < DVOL);
        const int zs = min(max(zc, 0), DVOL - 1);
#pragma unroll
        for (int dy = 0; dy < 2; ++dy) {
            const float wgy = dy ? wy : 1.0f - wy;
            const int yc = y0 + dy;
            const bool vy = (yc >= 0) && (yc < HVOL);
            const int ys = min(max(yc, 0), HVOL - 1);
#pragma unroll
            for (int dx = 0; dx < 2; ++dx) {
                const float wgx = dx ? wx : 1.0f - wx;
                const int xc = x0 + dx;
                const bool vx = (xc >= 0) && (xc < WVOL);
                const int xs = min(max(xc, 0), WVOL - 1);
                const float wgt =
                    wgz * wgy * wgx * ((vz && vy && vx) ? 1.0f : 0.0f);
                const size_t base = ((size_t)zs * HVOL + ys) * (size_t)WVOL + xs;
                acc0 += f[base] * wgt;
                acc1 += f[base + cstride] * wgt;
                acc2 += f[base + 2 * cstride] * wgt;
            }
        }
    }

    // project onto (pv, pw, n)
    const float p0 = acc0 * B.pvx + acc1 * B.pvy + acc2 * B.pvz;
    const float p1 = acc0 * B.pwx + acc1 * B.pwy + acc2 * B.pwz;
    const float p2 = acc0 * B.nx  + acc1 * B.ny  + acc2 * B.nz;
    if (fproj) { fproj[0] = p0; fproj[1] = p1; fproj[2] = p2; }

    // polar rotation by phi = atan2(gw, gv); sin/cos computed directly
    const float r = sqrtf(gv * gv + gw * gw);
    const float s = (r > 0.0f) ? gw / r : 0.0f;
    const float c = (r > 0.0f) ? gv / r : 1.0f;
    fpol[0] =  c * p0 + s * p1;
    fpol[1] = -s * p0 + c * p1;
    fpol[2] =  p2;
}

__global__ void planar_sample_grad_kernel(const float* __restrict__ f,
                                          const float* __restrict__ pn,
                                          const float* __restrict__ org,
                                          float* __restrict__ out)
{
    const int idx = blockIdx.x * blockDim.x + threadIdx.x;
    if (idx >= NPTS) return;
    const int h = idx / GSZ;
    const int w = idx - h * GSZ;

    // plane basis (cheap, recomputed per thread)
    Basis B;
    {
        float n0 = pn[0], n1 = pn[1], n2 = pn[2];
        const float nrm = sqrtf(n0 * n0 + n1 * n1 + n2 * n2);
        n0 /= nrm; n1 /= nrm; n2 /= nrm;
        const float beta = 1.0f / sqrtf(1.0f - n2 * n2);
        B.pvx = -n1 * beta; B.pvy = n0 * beta; B.pvz = 0.0f;
        B.pwx = -n2 * B.pvy; B.pwy = n2 * B.pvx; B.pwz = 1.0f / beta;
        B.nx = n0; B.ny = n1; B.nz = n2;
        B.ox = org[0]; B.oy = org[1]; B.oz = org[2];
    }

    float fc[3], fp[3];
    fpol_at(f, h, w, B, fc, fp);

    // output 0: f_p (vwn-projected), layout [n][h][w]
    out[0 * NPTS + idx] = fp[0];
    out[1 * NPTS + idx] = fp[1];
    out[2 * NPTS + idx] = fp[2];

    float t1[3], t2[3];
    float gxv[3], gyv[3];

    // gradient along w (last axis)
    if (w == 0) {
        fpol_at(f, h, 1, B, t1, nullptr);
        fpol_at(f, h, 2, B, t2, nullptr);
#pragma unroll
        for (int i = 0; i < 3; ++i)
            gxv[i] = -1.5f * fc[i] + 2.0f * t1[i] - 0.5f * t2[i];
    } else if (w == GSZ - 1) {
        fpol_at(f, h, GSZ - 2, B, t1, nullptr);
        fpol_at(f, h, GSZ - 3, B, t2, nullptr);
#pragma unroll
        for (int i = 0; i < 3; ++i)
            gxv[i] = 1.5f * fc[i] - 2.0f * t1[i] + 0.5f * t2[i];
    } else {
        fpol_at(f, h, w + 1, B, t1, nullptr);
        fpol_at(f, h, w - 1, B, t2, nullptr);
#pragma unroll
        for (int i = 0; i < 3; ++i)
            gxv[i] = 0.5f * (t1[i] - t2[i]);
    }

    // gradient along h (second-to-last axis)
    if (h == 0) {
        fpol_at(f, 1, w, B, t1, nullptr);
        fpol_at(f, 2, w, B, t2, nullptr);
#pragma unroll
        for (int i = 0; i < 3; ++i)
            gyv[i] = -1.5f * fc[i] + 2.0f * t1[i] - 0.5f * t2[i];
    } else if (h == GSZ - 1) {
        fpol_at(f, GSZ - 2, w, B, t1, nullptr);
        fpol_at(f, GSZ - 3, w, B, t2, nullptr);
#pragma unroll
        for (int i = 0; i < 3; ++i)
            gyv[i] = 1.5f * fc[i] - 2.0f * t1[i] + 0.5f * t2[i];
    } else {
        fpol_at(f, h + 1, w, B, t1, nullptr);
        fpol_at(f, h - 1, w, B, t2, nullptr);
#pragma unroll
        for (int i = 0; i < 3; ++i)
            gyv[i] = 0.5f * (t1[i] - t2[i]);
    }

    // rotate gradient vector (gx, gy, 0) by P at the CENTER point's phi
    const float gv = (float)(w - 48);
    const float gw = (float)(h - 48);
    const float r = sqrtf(gv * gv + gw * gw);
    const float s = (r > 0.0f) ? gw / r : 0.0f;
    const float c = (r > 0.0f) ? gv / r : 1.0f;

    float* __restrict__ o2 = out + 3 * NPTS;
#pragma unroll
    for (int i = 0; i < 3; ++i) {
        o2[(0 * 3 + i) * NPTS + idx] =  c * gxv[i] + s * gyv[i];
        o2[(1 * 3 + i) * NPTS + idx] = -s * gxv[i] + c * gyv[i];
        o2[(2 * 3 + i) * NPTS + idx] = 0.0f;
    }
}

extern "C" void kernel_launch(void* const* d_in, const int* in_sizes, int n_in,
                              void* d_out, int out_size, void* d_ws, size_t ws_size,
                              hipStream_t stream) {
    const float* f   = (const float*)d_in[0];
    const float* pn  = (const float*)d_in[1];
    const float* org = (const float*)d_in[2];
    float* out = (float*)d_out;

    const int block = 256;
    const int grid = (NPTS + block - 1) / block;
    planar_sample_grad_kernel<<<grid, block, 0, stream>>>(f, pn, org, out);
}

// Round 2
// 11.092 us; speedup vs baseline: 1.9265x; 1.9265x over previous
//
#include <hip/hip_runtime.h>

#define GSZ   97
#define NPTS  (GSZ * GSZ)
#define DVOL  150
#define HVOL  512
#define WVOL  512
#define TILE  16
#define HALO  2
#define SPAN  (TILE + 2 * HALO)   // 20
#define NTILE ((GSZ + TILE - 1) / TILE)  // 7

struct Basis {
    float pvx, pvy, pvz;
    float pwx, pwy, pwz;
    float nx,  ny,  nz;
    float ox,  oy,  oz;
};

// Trilinear sample + vwn projection + polar rotation at grid point (h, w).
// fpol: polar-rotated 3-vector. fproj: vwn-projected 3-vector (pre-rotation).
__device__ inline void fpol_at(const float* __restrict__ f, int h, int w,
                               const Basis& B, float* __restrict__ fpol,
                               float* __restrict__ fproj)
{
    const float gv = (float)(w - 48);   // v value = gxy[w]
    const float gw = (float)(h - 48);   // w value = gxy[h]

    const float px = gv * B.pvx + gw * B.pwx + B.ox;
    const float py = gv * B.pvy + gw * B.pwy + B.oy;
    const float pz = gv * B.pvz + gw * B.pwz + B.oz;

    const float EPSF = 1e-8f;
    const float gnx = px * (2.0f / ((float)WVOL - 1.0f + EPSF)) - 1.0f;
    const float gny = py * (2.0f / ((float)HVOL - 1.0f + EPSF)) - 1.0f;
    const float gnz = pz * (2.0f / ((float)DVOL - 1.0f + EPSF)) - 1.0f;
    const float ix = ((gnx + 1.0f) * (float)WVOL - 1.0f) * 0.5f;
    const float iy = ((gny + 1.0f) * (float)HVOL - 1.0f) * 0.5f;
    const float iz = ((gnz + 1.0f) * (float)DVOL - 1.0f) * 0.5f;

    const float x0f = floorf(ix), y0f = floorf(iy), z0f = floorf(iz);
    const float wx = ix - x0f, wy = iy - y0f, wz = iz - z0f;
    const int x0 = (int)x0f, y0 = (int)y0f, z0 = (int)z0f;

    const size_t cstride = (size_t)DVOL * HVOL * WVOL;

    float acc0 = 0.0f, acc1 = 0.0f, acc2 = 0.0f;
#pragma unroll
    for (int dz = 0; dz < 2; ++dz) {
        const float wgz = dz ? wz : 1.0f - wz;
        const int zc = z0 + dz;
        const bool vz = (zc >= 0) && (zc < DVOL);
        const int zs = min(max(zc, 0), DVOL - 1);
#pragma unroll
        for (int dy = 0; dy < 2; ++dy) {
            const float wgy = dy ? wy : 1.0f - wy;
            const int yc = y0 + dy;
            const bool vy = (yc >= 0) && (yc < HVOL);
            const int ys = min(max(yc, 0), HVOL - 1);
#pragma unroll
            for (int dx = 0; dx < 2; ++dx) {
                const float wgx = dx ? wx : 1.0f - wx;
                const int xc = x0 + dx;
                const bool vx = (xc >= 0) && (xc < WVOL);
                const int xs = min(max(xc, 0), WVOL - 1);
                const float wgt =
                    wgz * wgy * wgx * ((vz && vy && vx) ? 1.0f : 0.0f);
                const size_t base = ((size_t)zs * HVOL + ys) * (size_t)WVOL + xs;
                acc0 += f[base] * wgt;
                acc1 += f[base + cstride] * wgt;
                acc2 += f[base + 2 * cstride] * wgt;
            }
        }
    }

    const float p0 = acc0 * B.pvx + acc1 * B.pvy + acc2 * B.pvz;
    const float p1 = acc0 * B.pwx + acc1 * B.pwy + acc2 * B.pwz;
    const float p2 = acc0 * B.nx  + acc1 * B.ny  + acc2 * B.nz;
    fproj[0] = p0; fproj[1] = p1; fproj[2] = p2;

    const float r = sqrtf(gv * gv + gw * gw);
    const float s = (r > 0.0f) ? gw / r : 0.0f;
    const float c = (r > 0.0f) ? gv / r : 1.0f;
    fpol[0] =  c * p0 + s * p1;
    fpol[1] = -s * p0 + c * p1;
    fpol[2] =  p2;
}

__global__ __launch_bounds__(512)
void planar_tile_kernel(const float* __restrict__ f,
                        const float* __restrict__ pn,
                        const float* __restrict__ org,
                        float* __restrict__ out)
{
    __shared__ float spol[SPAN][SPAN][3];

    const int r0 = blockIdx.y * TILE;
    const int c0 = blockIdx.x * TILE;
    const int tid = threadIdx.x;

    // plane basis (cheap, broadcast loads)
    Basis B;
    {
        float n0 = pn[0], n1 = pn[1], n2 = pn[2];
        const float nrm = sqrtf(n0 * n0 + n1 * n1 + n2 * n2);
        n0 /= nrm; n1 /= nrm; n2 /= nrm;
        const float beta = 1.0f / sqrtf(1.0f - n2 * n2);
        B.pvx = -n1 * beta; B.pvy = n0 * beta; B.pvz = 0.0f;
        B.pwx = -n2 * B.pvy; B.pwy = n2 * B.pvx; B.pwz = 1.0f / beta;
        B.nx = n0; B.ny = n1; B.nz = n2;
        B.ox = org[0]; B.oy = org[1]; B.oz = org[2];
    }

    // Phase 1: fill the (TILE+2*HALO)^2 f_pol patch (one eval per point, once).
    for (int e = tid; e < SPAN * SPAN; e += (int)blockDim.x) {
        const int sr = e / SPAN;
        const int sc = e - sr * SPAN;
        const int gh = r0 - HALO + sr;
        const int gw = c0 - HALO + sc;
        if (gh >= 0 && gh < GSZ && gw >= 0 && gw < GSZ) {
            float fpol[3], fproj[3];
            fpol_at(f, gh, gw, B, fpol, fproj);
            spol[sr][sc][0] = fpol[0];
            spol[sr][sc][1] = fpol[1];
            spol[sr][sc][2] = fpol[2];
            // output 0: f_p, written once by the owning tile
            if (gh >= r0 && gh < r0 + TILE && gw >= c0 && gw < c0 + TILE) {
                const int idx = gh * GSZ + gw;
                out[0 * NPTS + idx] = fproj[0];
                out[1 * NPTS + idx] = fproj[1];
                out[2 * NPTS + idx] = fproj[2];
            }
        }
    }

    __syncthreads();

    // Phase 2: 256 threads -> 16x16 output points; gradients from LDS.
    if (tid >= TILE * TILE) return;
    const int lr = tid >> 4;
    const int lc = tid & 15;
    const int h = r0 + lr;
    const int w = c0 + lc;
    if (h >= GSZ || w >= GSZ) return;

    const int sr = lr + HALO;
    const int sc = lc + HALO;

    float gxv[3], gyv[3];

    // d/dw (last axis)
    if (w == 0) {
        // local cols for global w=0,1,2 (c0==0 here): sc = 2,3,4
#pragma unroll
        for (int i = 0; i < 3; ++i)
            gxv[i] = -1.5f * spol[sr][2][i] + 2.0f * spol[sr][3][i]
                     - 0.5f * spol[sr][4][i];
    } else if (w == GSZ - 1) {
        const int b = (GSZ - 1) - c0 + HALO;  // local col of w=96
#pragma unroll
        for (int i = 0; i < 3; ++i)
            gxv[i] = 1.5f * spol[sr][b][i] - 2.0f * spol[sr][b - 1][i]
                     + 0.5f * spol[sr][b - 2][i];
    } else {
#pragma unroll
        for (int i = 0; i < 3; ++i)
            gxv[i] = 0.5f * (spol[sr][sc + 1][i] - spol[sr][sc - 1][i]);
    }

    // d/dh (second-to-last axis)
    if (h == 0) {
#pragma unroll
        for (int i = 0; i < 3; ++i)
            gyv[i] = -1.5f * spol[2][sc][i] + 2.0f * spol[3][sc][i]
                     - 0.5f * spol[4][sc][i];
    } else if (h == GSZ - 1) {
        const int b = (GSZ - 1) - r0 + HALO;  // local row of h=96
#pragma unroll
        for (int i = 0; i < 3; ++i)
            gyv[i] = 1.5f * spol[b][sc][i] - 2.0f * spol[b - 1][sc][i]
                     + 0.5f * spol[b - 2][sc][i];
    } else {
#pragma unroll
        for (int i = 0; i < 3; ++i)
            gyv[i] = 0.5f * (spol[sr + 1][sc][i] - spol[sr - 1][sc][i]);
    }

    // rotate gradient vector (gx, gy, 0) by P at the center point's phi
    const float gv = (float)(w - 48);
    const float gw = (float)(h - 48);
    const float r = sqrtf(gv * gv + gw * gw);
    const float s = (r > 0.0f) ? gw / r : 0.0f;
    const float c = (r > 0.0f) ? gv / r : 1.0f;

    const int idx = h * GSZ + w;
    float* __restrict__ o2 = out + 3 * NPTS;
#pragma unroll
    for (int i = 0; i < 3; ++i) {
        o2[(0 * 3 + i) * NPTS + idx] =  c * gxv[i] + s * gyv[i];
        o2[(1 * 3 + i) * NPTS + idx] = -s * gxv[i] + c * gyv[i];
        o2[(2 * 3 + i) * NPTS + idx] = 0.0f;
    }
}

extern "C" void kernel_launch(void* const* d_in, const int* in_sizes, int n_in,
                              void* d_out, int out_size, void* d_ws, size_t ws_size,
                              hipStream_t stream) {
    const float* f   = (const float*)d_in[0];
    const float* pn  = (const float*)d_in[1];
    const float* org = (const float*)d_in[2];
    float* out = (float*)d_out;

    dim3 grid(NTILE, NTILE);
    planar_tile_kernel<<<grid, 512, 0, stream>>>(f, pn, org, out);
}